// Round 1
// baseline (2074.282 us; speedup 1.0000x reference)
//
#include <hip/hip_runtime.h>
#include <hip/hip_bf16.h>

// Problem constants (fixed by reference setup_inputs)
#define BATCH 4
#define SEQ 2048
#define DM 1024
#define NH 16
#define DK 64
#define DFF 4096
#define NTOK (BATCH*SEQ)   // 8192

typedef unsigned short u16;
typedef __attribute__((ext_vector_type(8))) short short8;
typedef __attribute__((ext_vector_type(4))) float floatx4;

__device__ __forceinline__ float bf2f(u16 u) {
    return __uint_as_float(((unsigned)u) << 16);
}
__device__ __forceinline__ u16 f2bf(float f) {
    unsigned u = __float_as_uint(f);
    u = (u + 0x7fffu + ((u >> 16) & 1u)) >> 16;
    return (u16)u;
}

// ---------------------------------------------------------------------------
// Weight transpose + fp32->bf16 cast:  W[K][N] row-major -> Wt[N][K] bf16
// ---------------------------------------------------------------------------
__global__ __launch_bounds__(256) void wtrans_kernel(const float* __restrict__ W,
                                                     u16* __restrict__ Wt,
                                                     int K, int N) {
    __shared__ float tile[32][33];
    int n0 = blockIdx.x * 32, k0 = blockIdx.y * 32;
    int tx = threadIdx.x, ty = threadIdx.y;   // block (32,8)
    for (int i = 0; i < 4; i++)
        tile[ty + 8 * i][tx] = W[(long)(k0 + ty + 8 * i) * N + n0 + tx];
    __syncthreads();
    for (int i = 0; i < 4; i++)
        Wt[(long)(n0 + ty + 8 * i) * K + k0 + tx] = f2bf(tile[tx][ty + 8 * i]);
}

// ---------------------------------------------------------------------------
// LayerNorm: fp32 [rows][1024] -> bf16 [rows][1024], one block per row
// ---------------------------------------------------------------------------
__global__ __launch_bounds__(256) void ln_kernel(const float* __restrict__ x,
                                                 const float* __restrict__ g,
                                                 const float* __restrict__ bb,
                                                 u16* __restrict__ out) {
    int row = blockIdx.x;
    int t = threadIdx.x;
    const float4* xr = (const float4*)(x + (long)row * DM);
    float4 v = xr[t];
    float s = v.x + v.y + v.z + v.w;
    float ss = v.x * v.x + v.y * v.y + v.z * v.z + v.w * v.w;
    for (int off = 32; off; off >>= 1) {
        s += __shfl_down(s, off);
        ss += __shfl_down(ss, off);
    }
    __shared__ float red[8];
    int wave = t >> 6, lane = t & 63;
    if (lane == 0) { red[wave] = s; red[4 + wave] = ss; }
    __syncthreads();
    if (t == 0) {
        red[0] = red[0] + red[1] + red[2] + red[3];
        red[4] = red[4] + red[5] + red[6] + red[7];
    }
    __syncthreads();
    float mean = red[0] * (1.0f / DM);
    float var = red[4] * (1.0f / DM) - mean * mean;
    float rstd = rsqrtf(var + 1e-5f);
    float4 gv = ((const float4*)g)[t];
    float4 bv = ((const float4*)bb)[t];
    u16 o0 = f2bf((v.x - mean) * rstd * gv.x + bv.x);
    u16 o1 = f2bf((v.y - mean) * rstd * gv.y + bv.y);
    u16 o2 = f2bf((v.z - mean) * rstd * gv.z + bv.z);
    u16 o3 = f2bf((v.w - mean) * rstd * gv.w + bv.w);
    u16* op = out + (long)row * DM + t * 4;
    op[0] = o0; op[1] = o1; op[2] = o2; op[3] = o3;
}

// ---------------------------------------------------------------------------
// bf16 MFMA GEMM: C[M][N] = A[M][K] @ Bt[N][K]^T (+bias, +gelu, +res)
// 128x128 tile, BK=32, 256 threads = 4 waves, each wave 64x64 via 4x4 mfma
// flags: bit0 = out bf16, bit1 = gelu.  res != nullptr -> add residual (fp32)
// ---------------------------------------------------------------------------
__global__ __launch_bounds__(256) void gemm_kernel(const u16* __restrict__ A,
                                                   const u16* __restrict__ Bt,
                                                   const float* __restrict__ bias,
                                                   const float* __restrict__ res,
                                                   void* __restrict__ out,
                                                   int M, int N, int K, int flags) {
    __shared__ __align__(16) u16 As[128 * 40];   // 128 rows x 32 (+8 pad)
    __shared__ __align__(16) u16 Bs[128 * 40];
    int t = threadIdx.x;
    int m0 = blockIdx.y * 128, n0 = blockIdx.x * 128;
    int w = t >> 6, l = t & 63;
    int wr = w >> 1, wc = w & 1;
    int lm = l & 15, lq = l >> 4;
    int arow = t >> 2, ac4 = t & 3;

    floatx4 acc[4][4];
    for (int i = 0; i < 4; i++)
        for (int j = 0; j < 4; j++)
            for (int r = 0; r < 4; r++) acc[i][j][r] = 0.0f;

    for (int kt = 0; kt < K; kt += 32) {
        __syncthreads();
        {
            const uint4* ga = (const uint4*)(A + (long)(m0 + arow) * K + kt);
            *(uint4*)&As[arow * 40 + ac4 * 8] = ga[ac4];
            const uint4* ga2 = (const uint4*)(A + (long)(m0 + arow + 64) * K + kt);
            *(uint4*)&As[(arow + 64) * 40 + ac4 * 8] = ga2[ac4];
            const uint4* gb = (const uint4*)(Bt + (long)(n0 + arow) * K + kt);
            *(uint4*)&Bs[arow * 40 + ac4 * 8] = gb[ac4];
            const uint4* gb2 = (const uint4*)(Bt + (long)(n0 + arow + 64) * K + kt);
            *(uint4*)&Bs[(arow + 64) * 40 + ac4 * 8] = gb2[ac4];
        }
        __syncthreads();
        short8 a[4], b[4];
        for (int i = 0; i < 4; i++)
            a[i] = *(const short8*)&As[(64 * wr + 16 * i + lm) * 40 + lq * 8];
        for (int j = 0; j < 4; j++)
            b[j] = *(const short8*)&Bs[(64 * wc + 16 * j + lm) * 40 + lq * 8];
        for (int i = 0; i < 4; i++)
            for (int j = 0; j < 4; j++)
                acc[i][j] = __builtin_amdgcn_mfma_f32_16x16x32_bf16(a[i], b[j], acc[i][j], 0, 0, 0);
    }

    bool obf = (flags & 1) != 0, gelu = (flags & 2) != 0;
    for (int i = 0; i < 4; i++) {
        int row = m0 + 64 * wr + 16 * i + lq * 4;
        for (int j = 0; j < 4; j++) {
            int col = n0 + 64 * wc + 16 * j + lm;
            float bcol = bias[col];
            for (int r = 0; r < 4; r++) {
                float v = acc[i][j][r] + bcol;
                if (gelu) v = 0.5f * v * (1.0f + erff(v * 0.70710678118f));
                long idx = (long)(row + r) * N + col;
                if (res) v += res[idx];
                if (obf) ((u16*)out)[idx] = f2bf(v);
                else ((float*)out)[idx] = v;
            }
        }
    }
}

// ---------------------------------------------------------------------------
// Flash attention (fp32 compute, bf16 I/O). Q,K,V: [B,S,DM] bf16, head slice
// cols h*64..h*64+63. Block: 64 queries x one (b,h); 256 threads (16x16),
// thread (ty,tx) owns q rows ty*4..+4, dims/keys tx*4..+4.
// ---------------------------------------------------------------------------
__global__ __launch_bounds__(256) void attn_kernel(const u16* __restrict__ Q,
                                                   const u16* __restrict__ Kb,
                                                   const u16* __restrict__ V,
                                                   const int* __restrict__ mask,
                                                   u16* __restrict__ ctx) {
    __shared__ __align__(16) float Qs[64][68];
    __shared__ __align__(16) u16 Ks[64][72];
    __shared__ __align__(16) float Vs[64][68];
    __shared__ __align__(16) float Ps[64][68];
    int t = threadIdx.x;
    int b = blockIdx.z, h = blockIdx.y, q0 = blockIdx.x * 64;
    int tx = t & 15, ty = t >> 4;

    // stage Q tile (bf16 -> fp32)
    for (int p = 0; p < 2; p++) {
        int cc = t + 256 * p;
        int row = cc >> 3, c8 = cc & 7;
        const uint4* gq = (const uint4*)(Q + ((long)(b * SEQ + q0 + row) * DM + h * DK));
        uint4 u = gq[c8];
        u16* us = (u16*)&u;
        for (int e = 0; e < 8; e++) Qs[row][c8 * 8 + e] = bf2f(us[e]);
    }

    float m_i[4], l_i[4], O[4][4];
    for (int i = 0; i < 4; i++) {
        m_i[i] = -1e30f; l_i[i] = 0.0f;
        for (int j = 0; j < 4; j++) O[i][j] = 0.0f;
    }

    for (int kt = 0; kt < SEQ; kt += 64) {
        __syncthreads();
        for (int p = 0; p < 2; p++) {
            int cc = t + 256 * p;
            int row = cc >> 3, c8 = cc & 7;
            const uint4* gk = (const uint4*)(Kb + ((long)(b * SEQ + kt + row) * DM + h * DK));
            *(uint4*)&Ks[row][c8 * 8] = gk[c8];
            const uint4* gv = (const uint4*)(V + ((long)(b * SEQ + kt + row) * DM + h * DK));
            uint4 uv = gv[c8];
            u16* us = (u16*)&uv;
            for (int e = 0; e < 8; e++) Vs[row][c8 * 8 + e] = bf2f(us[e]);
        }
        __syncthreads();

        float s[4][4] = {};
        for (int d = 0; d < 64; d++) {
            float qv[4], kv[4];
            for (int i = 0; i < 4; i++) qv[i] = Qs[ty * 4 + i][d];
            for (int j = 0; j < 4; j++) kv[j] = bf2f(Ks[tx * 4 + j][d]);
            for (int i = 0; i < 4; i++)
                for (int j = 0; j < 4; j++) s[i][j] += qv[i] * kv[j];
        }
        for (int j = 0; j < 4; j++) {
            int mk = mask[b * SEQ + kt + tx * 4 + j];
            for (int i = 0; i < 4; i++) {
                s[i][j] *= 0.125f;
                if (!mk) s[i][j] = -1e30f;
            }
        }
        float mt[4];
        for (int i = 0; i < 4; i++)
            mt[i] = fmaxf(fmaxf(s[i][0], s[i][1]), fmaxf(s[i][2], s[i][3]));
        for (int x = 1; x < 16; x <<= 1)
            for (int i = 0; i < 4; i++) mt[i] = fmaxf(mt[i], __shfl_xor(mt[i], x));
        float alpha[4], rs[4];
        for (int i = 0; i < 4; i++) {
            float mn = fmaxf(m_i[i], mt[i]);
            alpha[i] = __expf(m_i[i] - mn);
            m_i[i] = mn;
            float acc = 0.0f;
            for (int j = 0; j < 4; j++) {
                float pr = __expf(s[i][j] - mn);
                Ps[ty * 4 + i][tx * 4 + j] = pr;
                acc += pr;
            }
            rs[i] = acc;
        }
        for (int x = 1; x < 16; x <<= 1)
            for (int i = 0; i < 4; i++) rs[i] += __shfl_xor(rs[i], x);
        for (int i = 0; i < 4; i++) {
            l_i[i] = alpha[i] * l_i[i] + rs[i];
            for (int j = 0; j < 4; j++) O[i][j] *= alpha[i];
        }
        __syncthreads();
        for (int k = 0; k < 64; k++) {
            float pv[4], vv[4];
            for (int i = 0; i < 4; i++) pv[i] = Ps[ty * 4 + i][k];
            for (int j = 0; j < 4; j++) vv[j] = Vs[k][tx * 4 + j];
            for (int i = 0; i < 4; i++)
                for (int j = 0; j < 4; j++) O[i][j] += pv[i] * vv[j];
        }
    }

    for (int i = 0; i < 4; i++) {
        float inv = 1.0f / l_i[i];
        long row = (long)(b * SEQ + q0 + ty * 4 + i);
        for (int j = 0; j < 4; j++)
            ctx[row * DM + h * DK + tx * 4 + j] = f2bf(O[i][j] * inv);
    }
}

// ---------------------------------------------------------------------------
// Launch
// ---------------------------------------------------------------------------
extern "C" void kernel_launch(void* const* d_in, const int* in_sizes, int n_in,
                              void* d_out, int out_size, void* d_ws, size_t ws_size,
                              hipStream_t stream) {
    const float* x    = (const float*)d_in[0];
    const int*   mask = (const int*)d_in[1];
    const float* Wq = (const float*)d_in[2];  const float* bq = (const float*)d_in[3];
    const float* Wk = (const float*)d_in[4];  const float* bk = (const float*)d_in[5];
    const float* Wv = (const float*)d_in[6];  const float* bv = (const float*)d_in[7];
    const float* Wo = (const float*)d_in[8];  const float* bo = (const float*)d_in[9];
    const float* W1 = (const float*)d_in[10]; const float* b1 = (const float*)d_in[11];
    const float* W2 = (const float*)d_in[12]; const float* b2 = (const float*)d_in[13];
    const float* ln1g = (const float*)d_in[14]; const float* ln1b = (const float*)d_in[15];
    const float* ln2g = (const float*)d_in[16]; const float* ln2b = (const float*)d_in[17];

    char* ws = (char*)d_ws;
    const size_t MB = 1u << 20;
    // peak ws usage: 136 MB (H2 reuses the Q/K/V/CTX region)
    u16* WqT = (u16*)(ws + 0 * MB);
    u16* WkT = (u16*)(ws + 2 * MB);
    u16* WvT = (u16*)(ws + 4 * MB);
    u16* WoT = (u16*)(ws + 6 * MB);
    u16* W1T = (u16*)(ws + 8 * MB);
    u16* W2T = (u16*)(ws + 16 * MB);
    u16* Hbf = (u16*)(ws + 24 * MB);   // LN output, bf16 [8192][1024]
    u16* Qb  = (u16*)(ws + 40 * MB);
    u16* Kb  = (u16*)(ws + 56 * MB);
    u16* Vb  = (u16*)(ws + 72 * MB);
    u16* CTX = (u16*)(ws + 88 * MB);
    float* X2 = (float*)(ws + 104 * MB); // fp32 [8192][1024]
    u16* H2  = (u16*)(ws + 40 * MB);     // bf16 [8192][4096], reuses Q/K/V/CTX

    dim3 tb(32, 8);
    wtrans_kernel<<<dim3(DM / 32, DM / 32), tb, 0, stream>>>(Wq, WqT, DM, DM);
    wtrans_kernel<<<dim3(DM / 32, DM / 32), tb, 0, stream>>>(Wk, WkT, DM, DM);
    wtrans_kernel<<<dim3(DM / 32, DM / 32), tb, 0, stream>>>(Wv, WvT, DM, DM);
    wtrans_kernel<<<dim3(DM / 32, DM / 32), tb, 0, stream>>>(Wo, WoT, DM, DM);
    wtrans_kernel<<<dim3(DFF / 32, DM / 32), tb, 0, stream>>>(W1, W1T, DM, DFF);
    wtrans_kernel<<<dim3(DM / 32, DFF / 32), tb, 0, stream>>>(W2, W2T, DFF, DM);

    // ln1
    ln_kernel<<<NTOK, 256, 0, stream>>>(x, ln1g, ln1b, Hbf);

    // Q,K,V projections (bf16 out, bias)
    gemm_kernel<<<dim3(DM / 128, NTOK / 128), 256, 0, stream>>>(Hbf, WqT, bq, nullptr, Qb, NTOK, DM, DM, 1);
    gemm_kernel<<<dim3(DM / 128, NTOK / 128), 256, 0, stream>>>(Hbf, WkT, bk, nullptr, Kb, NTOK, DM, DM, 1);
    gemm_kernel<<<dim3(DM / 128, NTOK / 128), 256, 0, stream>>>(Hbf, WvT, bv, nullptr, Vb, NTOK, DM, DM, 1);

    // attention
    attn_kernel<<<dim3(SEQ / 64, NH, BATCH), 256, 0, stream>>>(Qb, Kb, Vb, mask, CTX);

    // x2 = x + ctx @ Wo + bo (fp32 out)
    gemm_kernel<<<dim3(DM / 128, NTOK / 128), 256, 0, stream>>>(CTX, WoT, bo, x, X2, NTOK, DM, DM, 0);

    // ln2
    ln_kernel<<<NTOK, 256, 0, stream>>>(X2, ln2g, ln2b, Hbf);

    // h2 = gelu(h @ W1 + b1) (bf16 out)
    gemm_kernel<<<dim3(DFF / 128, NTOK / 128), 256, 0, stream>>>(Hbf, W1T, b1, nullptr, H2, NTOK, DFF, DM, 3);

    // out = x2 + h2 @ W2 + b2 (fp32 out)
    gemm_kernel<<<dim3(DM / 128, NTOK / 128), 256, 0, stream>>>(H2, W2T, b2, X2, (float*)d_out, NTOK, DM, DFF, 0);
}

// Round 2
// 837.329 us; speedup vs baseline: 2.4773x; 2.4773x over previous
//
#include <hip/hip_runtime.h>
#include <hip/hip_bf16.h>

// Problem constants (fixed by reference setup_inputs)
#define BATCH 4
#define SEQ 2048
#define DM 1024
#define NH 16
#define DK 64
#define DFF 4096
#define NTOK (BATCH*SEQ)   // 8192

typedef unsigned short u16;
typedef __attribute__((ext_vector_type(8))) short short8;
typedef __attribute__((ext_vector_type(4))) float floatx4;

__device__ __forceinline__ float bf2f(u16 u) {
    return __uint_as_float(((unsigned)u) << 16);
}
__device__ __forceinline__ u16 f2bf(float f) {
    unsigned u = __float_as_uint(f);
    u = (u + 0x7fffu + ((u >> 16) & 1u)) >> 16;
    return (u16)u;
}

// async global->LDS, 16B per lane, LDS dest = uniform base + lane*16
#define GLOAD_LDS16(g, l) __builtin_amdgcn_global_load_lds( \
    (const __attribute__((address_space(1))) void*)(g),      \
    (__attribute__((address_space(3))) void*)(l), 16, 0, 0)

// ---------------------------------------------------------------------------
// Weight transpose + fp32->bf16 cast:  W[K][N] row-major -> Wt[N][K] bf16
// ---------------------------------------------------------------------------
__global__ __launch_bounds__(256) void wtrans_kernel(const float* __restrict__ W,
                                                     u16* __restrict__ Wt,
                                                     int K, int N) {
    __shared__ float tile[32][33];
    int n0 = blockIdx.x * 32, k0 = blockIdx.y * 32;
    int tx = threadIdx.x, ty = threadIdx.y;   // block (32,8)
    for (int i = 0; i < 4; i++)
        tile[ty + 8 * i][tx] = W[(long)(k0 + ty + 8 * i) * N + n0 + tx];
    __syncthreads();
    for (int i = 0; i < 4; i++)
        Wt[(long)(n0 + ty + 8 * i) * K + k0 + tx] = f2bf(tile[tx][ty + 8 * i]);
}

// ---------------------------------------------------------------------------
// V transpose: V[b*S+s][h*64+d] (bf16) -> Vt[((b*16+h)*64+d)*2048 + s]
// grid (SEQ/64, NH, BATCH), 256 threads, 64x64 bf16 tile
// ---------------------------------------------------------------------------
__global__ __launch_bounds__(256) void vtrans_kernel(const u16* __restrict__ V,
                                                     u16* __restrict__ Vt) {
    __shared__ __align__(16) u16 T[64 * 72];
    int t = threadIdx.x;
    int b = blockIdx.z, h = blockIdx.y, s0 = blockIdx.x * 64;
    for (int p = 0; p < 2; p++) {
        int c = t + 256 * p, row = c >> 3, c8 = c & 7;
        *(uint4*)&T[row * 72 + c8 * 8] =
            *(const uint4*)(V + (long)(b * SEQ + s0 + row) * DM + h * DK + c8 * 8);
    }
    __syncthreads();
    for (int p = 0; p < 2; p++) {
        int c = t + 256 * p, d = c >> 3, c8 = c & 7;
        u16 tmp[8];
        for (int e = 0; e < 8; e++) tmp[e] = T[(c8 * 8 + e) * 72 + d];
        *(uint4*)(Vt + ((long)(b * NH + h) * DK + d) * SEQ + s0 + c8 * 8) = *(uint4*)tmp;
    }
}

// ---------------------------------------------------------------------------
// LayerNorm: fp32 [rows][1024] -> bf16 [rows][1024], one block per row
// ---------------------------------------------------------------------------
__global__ __launch_bounds__(256) void ln_kernel(const float* __restrict__ x,
                                                 const float* __restrict__ g,
                                                 const float* __restrict__ bb,
                                                 u16* __restrict__ out) {
    int row = blockIdx.x;
    int t = threadIdx.x;
    const float4* xr = (const float4*)(x + (long)row * DM);
    float4 v = xr[t];
    float s = v.x + v.y + v.z + v.w;
    float ss = v.x * v.x + v.y * v.y + v.z * v.z + v.w * v.w;
    for (int off = 32; off; off >>= 1) {
        s += __shfl_down(s, off);
        ss += __shfl_down(ss, off);
    }
    __shared__ float red[8];
    int wave = t >> 6, lane = t & 63;
    if (lane == 0) { red[wave] = s; red[4 + wave] = ss; }
    __syncthreads();
    if (t == 0) {
        red[0] = red[0] + red[1] + red[2] + red[3];
        red[4] = red[4] + red[5] + red[6] + red[7];
    }
    __syncthreads();
    float mean = red[0] * (1.0f / DM);
    float var = red[4] * (1.0f / DM) - mean * mean;
    float rstd = rsqrtf(var + 1e-5f);
    float4 gv = ((const float4*)g)[t];
    float4 bv = ((const float4*)bb)[t];
    u16 o0 = f2bf((v.x - mean) * rstd * gv.x + bv.x);
    u16 o1 = f2bf((v.y - mean) * rstd * gv.y + bv.y);
    u16 o2 = f2bf((v.z - mean) * rstd * gv.z + bv.z);
    u16 o3 = f2bf((v.w - mean) * rstd * gv.w + bv.w);
    u16* op = out + (long)row * DM + t * 4;
    op[0] = o0; op[1] = o1; op[2] = o2; op[3] = o3;
}

// ---------------------------------------------------------------------------
// bf16 MFMA GEMM (m97-style): C[M][N] = A[M][K] @ Bt[N][K]^T (+bias,+gelu,+res)
// 128x128 tile, BK=32, 4 waves x (4x4) 16x16x32 mfma.
// LDS unpadded 64B rows (required by global_load_lds lane-ordered scatter;
// bank math: (row*16 + quad*4) mod 32 -> uniform 8 words/bank, no extra cost)
// flags: bit0 = out bf16, bit1 = gelu.  res != nullptr -> add residual (fp32)
// ---------------------------------------------------------------------------
__global__ __launch_bounds__(256) void gemm_kernel(const u16* __restrict__ A,
                                                   const u16* __restrict__ Bt,
                                                   const float* __restrict__ bias,
                                                   const float* __restrict__ res,
                                                   void* __restrict__ out,
                                                   int M, int N, int K, int flags) {
    __shared__ __align__(16) u16 As[128 * 32];
    __shared__ __align__(16) u16 Bs[128 * 32];
    int t = threadIdx.x;
    int m0 = blockIdx.y * 128, n0 = blockIdx.x * 128;
    int w = t >> 6, l = t & 63;
    int wr = w >> 1, wc = w & 1;
    int lm = l & 15, lq = l >> 4;

    // staging addressing: wave w, lane l covers row w*16 + (l>>2), 16B chunk l&3
    int srow = w * 16 + (l >> 2);
    int scol = (l & 3) * 8;

    floatx4 acc[4][4];
    for (int i = 0; i < 4; i++)
        for (int j = 0; j < 4; j++)
            for (int r = 0; r < 4; r++) acc[i][j][r] = 0.0f;

    for (int kt = 0; kt < K; kt += 32) {
        __syncthreads();
        GLOAD_LDS16(A + (long)(m0 + srow) * K + kt + scol, &As[w * 16 * 32]);
        GLOAD_LDS16(A + (long)(m0 + srow + 64) * K + kt + scol, &As[(w * 16 + 64) * 32]);
        GLOAD_LDS16(Bt + (long)(n0 + srow) * K + kt + scol, &Bs[w * 16 * 32]);
        GLOAD_LDS16(Bt + (long)(n0 + srow + 64) * K + kt + scol, &Bs[(w * 16 + 64) * 32]);
        __syncthreads();
        short8 a[4], b[4];
        for (int i = 0; i < 4; i++)
            a[i] = *(const short8*)&As[(64 * wr + 16 * i + lm) * 32 + lq * 8];
        for (int j = 0; j < 4; j++)
            b[j] = *(const short8*)&Bs[(64 * wc + 16 * j + lm) * 32 + lq * 8];
        for (int i = 0; i < 4; i++)
            for (int j = 0; j < 4; j++)
                acc[i][j] = __builtin_amdgcn_mfma_f32_16x16x32_bf16(a[i], b[j], acc[i][j], 0, 0, 0);
    }

    bool obf = (flags & 1) != 0, gelu = (flags & 2) != 0;
    for (int i = 0; i < 4; i++) {
        int row = m0 + 64 * wr + 16 * i + lq * 4;
        for (int j = 0; j < 4; j++) {
            int col = n0 + 64 * wc + 16 * j + lm;
            float bcol = bias[col];
            for (int r = 0; r < 4; r++) {
                float v = acc[i][j][r] + bcol;
                if (gelu) v = 0.5f * v * (1.0f + erff(v * 0.70710678118f));
                long idx = (long)(row + r) * N + col;
                if (res) v += res[idx];
                if (obf) ((u16*)out)[idx] = f2bf(v);
                else ((float*)out)[idx] = v;
            }
        }
    }
}

// ---------------------------------------------------------------------------
// MFMA flash attention. Q,K: [B,S,DM] bf16 (head slice h*64..+63),
// Vt: [B,H,Dk,S] bf16 (pre-transposed). Block = 64 queries x one (b,h),
// 4 waves, each wave owns 16 q-rows. K-tile = 64 keys.
// QK^T: A=Q (b128 from Qs), B=K^T (b128 from Ks rows).
// P: C-layout -> LDS (bf16) -> A-layout b128 reads (m120 pattern).
// PV:  B-frags b128 from Vt tile rows [d][key].
// All LDS pitches 72 (144B = 36 banks -> 4-bank/row shift, balanced).
// ---------------------------------------------------------------------------
__global__ __launch_bounds__(256) void attn_kernel(const u16* __restrict__ Q,
                                                   const u16* __restrict__ Kb,
                                                   const u16* __restrict__ Vt,
                                                   const int* __restrict__ mask,
                                                   u16* __restrict__ ctx) {
    __shared__ __align__(16) u16 Qs[64 * 72];
    __shared__ __align__(16) u16 Ks[64 * 72];
    __shared__ __align__(16) u16 Vs[64 * 72];   // [d][key]
    __shared__ __align__(16) u16 Ps[4 * 16 * 72]; // per-wave P [16 q][64 key]
    int t = threadIdx.x;
    int b = blockIdx.z, h = blockIdx.y, q0 = blockIdx.x * 64;
    int w = t >> 6, l = t & 63;
    int lm = l & 15, lq = l >> 4;
    u16* Pw = Ps + w * 16 * 72;

    // stage Q tile once (visibility covered by the loop's post-staging barrier)
    for (int p = 0; p < 2; p++) {
        int c = t + 256 * p, row = c >> 3, c8 = c & 7;
        *(uint4*)&Qs[row * 72 + c8 * 8] =
            *(const uint4*)(Q + (long)(b * SEQ + q0 + row) * DM + h * DK + c8 * 8);
    }

    floatx4 O[4];
    for (int j = 0; j < 4; j++)
        for (int r = 0; r < 4; r++) O[j][r] = 0.0f;
    float m_i[4], l_i[4];
    for (int r = 0; r < 4; r++) { m_i[r] = -1e30f; l_i[r] = 0.0f; }

    long kgbase = (long)(b * SEQ) * DM + h * DK;
    long vgbase = (long)(b * NH + h) * DK * SEQ;
    const int* mrow = mask + b * SEQ;

    for (int kt = 0; kt < SEQ; kt += 64) {
        __syncthreads();   // previous iter's LDS reads done before restaging
        for (int p = 0; p < 2; p++) {
            int c = t + 256 * p, row = c >> 3, c8 = c & 7;
            *(uint4*)&Ks[row * 72 + c8 * 8] =
                *(const uint4*)(Kb + kgbase + (long)(kt + row) * DM + c8 * 8);
            *(uint4*)&Vs[row * 72 + c8 * 8] =
                *(const uint4*)(Vt + vgbase + (long)row * SEQ + kt + c8 * 8);
        }
        __syncthreads();

        // ---- S = Q K^T ----
        short8 aq[2];
        for (int s = 0; s < 2; s++)
            aq[s] = *(const short8*)&Qs[(w * 16 + lm) * 72 + s * 32 + lq * 8];
        floatx4 S[4];
        for (int j = 0; j < 4; j++) {
            short8 b0 = *(const short8*)&Ks[(16 * j + lm) * 72 + lq * 8];
            short8 b1 = *(const short8*)&Ks[(16 * j + lm) * 72 + 32 + lq * 8];
            floatx4 z; z[0] = 0; z[1] = 0; z[2] = 0; z[3] = 0;
            S[j] = __builtin_amdgcn_mfma_f32_16x16x32_bf16(aq[0], b0, z, 0, 0, 0);
            S[j] = __builtin_amdgcn_mfma_f32_16x16x32_bf16(aq[1], b1, S[j], 0, 0, 0);
        }

        // ---- scale + mask + online softmax ----
        for (int j = 0; j < 4; j++) {
            int mk = mrow[kt + 16 * j + lm];
            for (int r = 0; r < 4; r++) {
                float v = S[j][r] * 0.125f;
                if (!mk) v = -1e30f;
                S[j][r] = v;
            }
        }
        float mx[4];
        for (int r = 0; r < 4; r++)
            mx[r] = fmaxf(fmaxf(S[0][r], S[1][r]), fmaxf(S[2][r], S[3][r]));
        for (int x = 1; x < 16; x <<= 1)
            for (int r = 0; r < 4; r++) mx[r] = fmaxf(mx[r], __shfl_xor(mx[r], x));
        float alpha[4], rs[4];
        for (int r = 0; r < 4; r++) {
            float mn = fmaxf(m_i[r], mx[r]);
            alpha[r] = __expf(m_i[r] - mn);
            m_i[r] = mn;
            rs[r] = 0.0f;
        }
        for (int j = 0; j < 4; j++)
            for (int r = 0; r < 4; r++) {
                float p = __expf(S[j][r] - m_i[r]);
                Pw[(lq * 4 + r) * 72 + 16 * j + lm] = f2bf(p);
                rs[r] += p;
            }
        for (int x = 1; x < 16; x <<= 1)
            for (int r = 0; r < 4; r++) rs[r] += __shfl_xor(rs[r], x);
        for (int r = 0; r < 4; r++)
            l_i[r] = alpha[r] * l_i[r] + rs[r];
        for (int j = 0; j < 4; j++)
            for (int r = 0; r < 4; r++) O[j][r] *= alpha[r];

        // ---- O += P V ----  (P write->read same wave; compiler inserts lgkmcnt)
        short8 ap[2];
        for (int s = 0; s < 2; s++)
            ap[s] = *(const short8*)&Pw[lm * 72 + s * 32 + lq * 8];
        for (int j = 0; j < 4; j++) {
            short8 v0 = *(const short8*)&Vs[(16 * j + lm) * 72 + lq * 8];
            short8 v1 = *(const short8*)&Vs[(16 * j + lm) * 72 + 32 + lq * 8];
            O[j] = __builtin_amdgcn_mfma_f32_16x16x32_bf16(ap[0], v0, O[j], 0, 0, 0);
            O[j] = __builtin_amdgcn_mfma_f32_16x16x32_bf16(ap[1], v1, O[j], 0, 0, 0);
        }
    }

    for (int r = 0; r < 4; r++) {
        float inv = 1.0f / l_i[r];
        long row = (long)(b * SEQ + q0 + w * 16 + lq * 4 + r);
        for (int j = 0; j < 4; j++)
            ctx[row * DM + h * DK + 16 * j + lm] = f2bf(O[j][r] * inv);
    }
}

// ---------------------------------------------------------------------------
// Launch
// ---------------------------------------------------------------------------
extern "C" void kernel_launch(void* const* d_in, const int* in_sizes, int n_in,
                              void* d_out, int out_size, void* d_ws, size_t ws_size,
                              hipStream_t stream) {
    const float* x    = (const float*)d_in[0];
    const int*   mask = (const int*)d_in[1];
    const float* Wq = (const float*)d_in[2];  const float* bq = (const float*)d_in[3];
    const float* Wk = (const float*)d_in[4];  const float* bk = (const float*)d_in[5];
    const float* Wv = (const float*)d_in[6];  const float* bv = (const float*)d_in[7];
    const float* Wo = (const float*)d_in[8];  const float* bo = (const float*)d_in[9];
    const float* W1 = (const float*)d_in[10]; const float* b1 = (const float*)d_in[11];
    const float* W2 = (const float*)d_in[12]; const float* b2 = (const float*)d_in[13];
    const float* ln1g = (const float*)d_in[14]; const float* ln1b = (const float*)d_in[15];
    const float* ln2g = (const float*)d_in[16]; const float* ln2b = (const float*)d_in[17];

    char* ws = (char*)d_ws;
    const size_t MB = 1u << 20;
    u16* WqT = (u16*)(ws + 0 * MB);
    u16* WkT = (u16*)(ws + 2 * MB);
    u16* WvT = (u16*)(ws + 4 * MB);
    u16* WoT = (u16*)(ws + 6 * MB);
    u16* W1T = (u16*)(ws + 8 * MB);
    u16* W2T = (u16*)(ws + 16 * MB);
    u16* Hbf = (u16*)(ws + 24 * MB);   // LN out bf16 [8192][1024]; later reused as Vt
    u16* Vtp = (u16*)(ws + 24 * MB);   // Vt [B][H][64][2048] bf16 (16MB), alive only attn
    u16* Qb  = (u16*)(ws + 40 * MB);
    u16* Kb  = (u16*)(ws + 56 * MB);
    u16* Vb  = (u16*)(ws + 72 * MB);
    u16* CTX = (u16*)(ws + 88 * MB);
    float* X2 = (float*)(ws + 104 * MB); // fp32 [8192][1024]
    u16* H2  = (u16*)(ws + 40 * MB);     // bf16 [8192][4096], reuses Q/K/V/CTX

    dim3 tb(32, 8);
    wtrans_kernel<<<dim3(DM / 32, DM / 32), tb, 0, stream>>>(Wq, WqT, DM, DM);
    wtrans_kernel<<<dim3(DM / 32, DM / 32), tb, 0, stream>>>(Wk, WkT, DM, DM);
    wtrans_kernel<<<dim3(DM / 32, DM / 32), tb, 0, stream>>>(Wv, WvT, DM, DM);
    wtrans_kernel<<<dim3(DM / 32, DM / 32), tb, 0, stream>>>(Wo, WoT, DM, DM);
    wtrans_kernel<<<dim3(DFF / 32, DM / 32), tb, 0, stream>>>(W1, W1T, DM, DFF);
    wtrans_kernel<<<dim3(DM / 32, DFF / 32), tb, 0, stream>>>(W2, W2T, DFF, DM);

    // ln1
    ln_kernel<<<NTOK, 256, 0, stream>>>(x, ln1g, ln1b, Hbf);

    // Q,K,V projections (bf16 out, bias)
    gemm_kernel<<<dim3(DM / 128, NTOK / 128), 256, 0, stream>>>(Hbf, WqT, bq, nullptr, Qb, NTOK, DM, DM, 1);
    gemm_kernel<<<dim3(DM / 128, NTOK / 128), 256, 0, stream>>>(Hbf, WkT, bk, nullptr, Kb, NTOK, DM, DM, 1);
    gemm_kernel<<<dim3(DM / 128, NTOK / 128), 256, 0, stream>>>(Hbf, WvT, bv, nullptr, Vb, NTOK, DM, DM, 1);

    // V -> Vt [B,H,Dk,S]  (Hbf dead after QKV gemms; region reused)
    vtrans_kernel<<<dim3(SEQ / 64, NH, BATCH), 256, 0, stream>>>(Vb, Vtp);

    // attention
    attn_kernel<<<dim3(SEQ / 64, NH, BATCH), 256, 0, stream>>>(Qb, Kb, Vtp, mask, CTX);

    // x2 = x + ctx @ Wo + bo (fp32 out)
    gemm_kernel<<<dim3(DM / 128, NTOK / 128), 256, 0, stream>>>(CTX, WoT, bo, x, X2, NTOK, DM, DM, 0);

    // ln2
    ln_kernel<<<NTOK, 256, 0, stream>>>(X2, ln2g, ln2b, Hbf);

    // h2 = gelu(h @ W1 + b1) (bf16 out)
    gemm_kernel<<<dim3(DFF / 128, NTOK / 128), 256, 0, stream>>>(Hbf, W1T, b1, nullptr, H2, NTOK, DFF, DM, 3);

    // out = x2 + h2 @ W2 + b2 (fp32 out)
    gemm_kernel<<<dim3(DM / 128, NTOK / 128), 256, 0, stream>>>(H2, W2T, b2, X2, (float*)d_out, NTOK, DM, DFF, 0);
}

// Round 4
// 694.254 us; speedup vs baseline: 2.9878x; 1.2061x over previous
//
#include <hip/hip_runtime.h>
#include <hip/hip_bf16.h>

// Problem constants (fixed by reference setup_inputs)
#define BATCH 4
#define SEQ 2048
#define DM 1024
#define NH 16
#define DK 64
#define DFF 4096
#define NTOK (BATCH*SEQ)   // 8192

typedef unsigned short u16;
typedef __attribute__((ext_vector_type(8))) short short8;
typedef __attribute__((ext_vector_type(4))) float floatx4;

__device__ __forceinline__ float bf2f(u16 u) {
    return __uint_as_float(((unsigned)u) << 16);
}
__device__ __forceinline__ u16 f2bf(float f) {
    unsigned u = __float_as_uint(f);
    u = (u + 0x7fffu + ((u >> 16) & 1u)) >> 16;
    return (u16)u;
}
// pack two f32 -> two bf16 (truncate) in ONE v_perm_b32: result = [bf(lo), bf(hi)]
__device__ __forceinline__ unsigned pack_bf16(float lo, float hi) {
    return __builtin_amdgcn_perm(__float_as_uint(hi), __float_as_uint(lo), 0x07060302u);
}

// ---------------------------------------------------------------------------
// Weight transpose + fp32->bf16 cast:  W[K][N] row-major -> Wt[N][K] bf16
// ---------------------------------------------------------------------------
__global__ __launch_bounds__(256) void wtrans_kernel(const float* __restrict__ W,
                                                     u16* __restrict__ Wt,
                                                     int K, int N) {
    __shared__ float tile[32][33];
    int n0 = blockIdx.x * 32, k0 = blockIdx.y * 32;
    int tx = threadIdx.x, ty = threadIdx.y;   // block (32,8)
    for (int i = 0; i < 4; i++)
        tile[ty + 8 * i][tx] = W[(long)(k0 + ty + 8 * i) * N + n0 + tx];
    __syncthreads();
    for (int i = 0; i < 4; i++)
        Wt[(long)(n0 + ty + 8 * i) * K + k0 + tx] = f2bf(tile[tx][ty + 8 * i]);
}

// bias concat bq|bk|bv -> 3072 floats
__global__ __launch_bounds__(256) void bconcat_kernel(const float* __restrict__ bq,
                                                      const float* __restrict__ bk,
                                                      const float* __restrict__ bv,
                                                      float* __restrict__ o) {
    int i = blockIdx.x * 256 + threadIdx.x;
    o[i] = (i < 1024) ? bq[i] : (i < 2048 ? bk[i - 1024] : bv[i - 2048]);
}

// additive mask: 0 where mask!=0 else -1e30
__global__ __launch_bounds__(256) void madd_kernel(const int* __restrict__ mask,
                                                   float* __restrict__ madd) {
    int i = blockIdx.x * 256 + threadIdx.x;
    madd[i] = mask[i] ? 0.0f : -1e30f;
}

// ---------------------------------------------------------------------------
// V transpose: QKV[b*S+s][2048 + h*64+d] (bf16, stride 3072)
//           -> Vt[((b*16+h)*64+d)*2048 + s]
// ---------------------------------------------------------------------------
__global__ __launch_bounds__(256) void vtrans_kernel(const u16* __restrict__ QKV,
                                                     u16* __restrict__ Vt) {
    __shared__ __align__(16) u16 T[64 * 72];
    int t = threadIdx.x;
    int b = blockIdx.z, h = blockIdx.y, s0 = blockIdx.x * 64;
    for (int p = 0; p < 2; p++) {
        int c = t + 256 * p, row = c >> 3, c8 = c & 7;
        *(uint4*)&T[row * 72 + c8 * 8] =
            *(const uint4*)(QKV + (long)(b * SEQ + s0 + row) * 3072 + 2048 + h * DK + c8 * 8);
    }
    __syncthreads();
    for (int p = 0; p < 2; p++) {
        int c = t + 256 * p, d = c >> 3, c8 = c & 7;
        u16 tmp[8];
        for (int e = 0; e < 8; e++) tmp[e] = T[(c8 * 8 + e) * 72 + d];
        *(uint4*)(Vt + ((long)(b * NH + h) * DK + d) * SEQ + s0 + c8 * 8) = *(uint4*)tmp;
    }
}

// ---------------------------------------------------------------------------
// LayerNorm: fp32 [rows][1024] -> bf16 [rows][1024], one block per row
// ---------------------------------------------------------------------------
__global__ __launch_bounds__(256) void ln_kernel(const float* __restrict__ x,
                                                 const float* __restrict__ g,
                                                 const float* __restrict__ bb,
                                                 u16* __restrict__ out) {
    int row = blockIdx.x;
    int t = threadIdx.x;
    const float4* xr = (const float4*)(x + (long)row * DM);
    float4 v = xr[t];
    float s = v.x + v.y + v.z + v.w;
    float ss = v.x * v.x + v.y * v.y + v.z * v.z + v.w * v.w;
    for (int off = 32; off; off >>= 1) {
        s += __shfl_down(s, off);
        ss += __shfl_down(ss, off);
    }
    __shared__ float red[8];
    int wave = t >> 6, lane = t & 63;
    if (lane == 0) { red[wave] = s; red[4 + wave] = ss; }
    __syncthreads();
    if (t == 0) {
        red[0] = red[0] + red[1] + red[2] + red[3];
        red[4] = red[4] + red[5] + red[6] + red[7];
    }
    __syncthreads();
    float mean = red[0] * (1.0f / DM);
    float var = red[4] * (1.0f / DM) - mean * mean;
    float rstd = rsqrtf(var + 1e-5f);
    float4 gv = ((const float4*)g)[t];
    float4 bv = ((const float4*)bb)[t];
    u16 o0 = f2bf((v.x - mean) * rstd * gv.x + bv.x);
    u16 o1 = f2bf((v.y - mean) * rstd * gv.y + bv.y);
    u16 o2 = f2bf((v.z - mean) * rstd * gv.z + bv.z);
    u16 o3 = f2bf((v.w - mean) * rstd * gv.w + bv.w);
    u16* op = out + (long)row * DM + t * 4;
    op[0] = o0; op[1] = o1; op[2] = o2; op[3] = o3;
}

// async global->LDS, 16B per lane, LDS dest = uniform base + lane*16
#define GLOAD_LDS16(g, l) __builtin_amdgcn_global_load_lds( \
    (const __attribute__((address_space(1))) void*)(g),      \
    (__attribute__((address_space(3))) void*)(l), 16, 0, 0)

// ---------------------------------------------------------------------------
// bf16 MFMA GEMM (m97-style): C[M][N] = A[M][K] @ Bt[N][K]^T (+bias,+gelu,+res)
// flags: bit0 = out bf16, bit1 = gelu, bit2 = qkv (scale cols<1024 by 0.125)
// ---------------------------------------------------------------------------
__global__ __launch_bounds__(256) void gemm_kernel(const u16* __restrict__ A,
                                                   const u16* __restrict__ Bt,
                                                   const float* __restrict__ bias,
                                                   const float* __restrict__ res,
                                                   void* __restrict__ out,
                                                   int M, int N, int K, int flags) {
    __shared__ __align__(16) u16 As[128 * 32];
    __shared__ __align__(16) u16 Bs[128 * 32];
    int t = threadIdx.x;
    int m0 = blockIdx.y * 128, n0 = blockIdx.x * 128;
    int w = t >> 6, l = t & 63;
    int wr = w >> 1, wc = w & 1;
    int lm = l & 15, lq = l >> 4;

    int srow = w * 16 + (l >> 2);
    int scol = (l & 3) * 8;

    floatx4 acc[4][4];
    for (int i = 0; i < 4; i++)
        for (int j = 0; j < 4; j++)
            for (int r = 0; r < 4; r++) acc[i][j][r] = 0.0f;

    for (int kt = 0; kt < K; kt += 32) {
        __syncthreads();
        GLOAD_LDS16(A + (long)(m0 + srow) * K + kt + scol, &As[w * 16 * 32]);
        GLOAD_LDS16(A + (long)(m0 + srow + 64) * K + kt + scol, &As[(w * 16 + 64) * 32]);
        GLOAD_LDS16(Bt + (long)(n0 + srow) * K + kt + scol, &Bs[w * 16 * 32]);
        GLOAD_LDS16(Bt + (long)(n0 + srow + 64) * K + kt + scol, &Bs[(w * 16 + 64) * 32]);
        __syncthreads();
        short8 a[4], b[4];
        for (int i = 0; i < 4; i++)
            a[i] = *(const short8*)&As[(64 * wr + 16 * i + lm) * 32 + lq * 8];
        for (int j = 0; j < 4; j++)
            b[j] = *(const short8*)&Bs[(64 * wc + 16 * j + lm) * 32 + lq * 8];
        for (int i = 0; i < 4; i++)
            for (int j = 0; j < 4; j++)
                acc[i][j] = __builtin_amdgcn_mfma_f32_16x16x32_bf16(a[i], b[j], acc[i][j], 0, 0, 0);
    }

    bool obf = (flags & 1) != 0, gelu = (flags & 2) != 0, qkv = (flags & 4) != 0;
    for (int i = 0; i < 4; i++) {
        int row = m0 + 64 * wr + 16 * i + lq * 4;
        for (int j = 0; j < 4; j++) {
            int col = n0 + 64 * wc + 16 * j + lm;
            float bcol = bias[col];
            float sc = (qkv && col < 1024) ? 0.125f : 1.0f;
            for (int r = 0; r < 4; r++) {
                float v = (acc[i][j][r] + bcol) * sc;
                if (gelu) v = 0.5f * v * (1.0f + erff(v * 0.70710678118f));
                long idx = (long)(row + r) * N + col;
                if (res) v += res[idx];
                if (obf) ((u16*)out)[idx] = f2bf(v);
                else ((float*)out)[idx] = v;
            }
        }
    }
}

// ---------------------------------------------------------------------------
// MFMA flash attention, S^T formulation.
// QKV: [B*S][3072] bf16 (Q cols 0-1023 pre-scaled by 0.125, K 1024-2047).
// Vt:  [B,H,Dk,S] bf16. Madd: [B*S] additive mask floats.
// Block = 64 queries x one (b,h); 4 waves, wave w owns q rows w*16..+15.
// S^T = K x Q^T: C-layout lane holds col q=lm, rows key=16j+lq*4+r
//  -> per-lane scalar m/l, 2-stage cross-quad reductions,
//  -> P rows contiguous along key: packed b64 writes, b128 A-frag reads.
// O = P x V: A=P frag, B=Vt tile rows [d][key]. Q LDS recycled as P buffer.
// K/V staging: 2x uint4/thread per tile (FULL 64x64 tile = 8 KB; 256 lanes
// x 16 B = 4 KB/pass -> 2 regs each), double-buffered through registers.
// ---------------------------------------------------------------------------
__global__ __launch_bounds__(256) void attn_kernel(const u16* __restrict__ QKV,
                                                   const u16* __restrict__ Vt,
                                                   const float* __restrict__ Madd,
                                                   u16* __restrict__ ctx) {
    __shared__ __align__(16) u16 Qs[64 * 72];   // recycled as P (2304 B per wave)
    __shared__ __align__(16) u16 Ks[64 * 72];
    __shared__ __align__(16) u16 Vs[64 * 72];   // [d][key]
    int t = threadIdx.x;
    int b = blockIdx.z, h = blockIdx.y, q0 = blockIdx.x * 64;
    int w = t >> 6, l = t & 63;
    int lm = l & 15, lq = l >> 4;
    int l4 = lq * 4;
    u16* Pw = Qs + w * 16 * 72;

    // stage full Q tile (2 passes: 512 uint4 chunks)
    for (int p = 0; p < 2; p++) {
        int c = t + 256 * p, row = c >> 3, c8 = c & 7;
        *(uint4*)&Qs[row * 72 + c8 * 8] =
            *(const uint4*)(QKV + (long)(b * SEQ + q0 + row) * 3072 + h * DK + c8 * 8);
    }
    __syncthreads();
    // hoisted Q B-fragments (loop-invariant)
    short8 qf0 = *(const short8*)&Qs[(w * 16 + lm) * 72 + lq * 8];
    short8 qf1 = *(const short8*)&Qs[(w * 16 + lm) * 72 + 32 + lq * 8];
    __syncthreads();   // all waves done reading Qs; region becomes P buffer

    floatx4 O[4];
    for (int dt = 0; dt < 4; dt++)
        for (int r = 0; r < 4; r++) O[dt][r] = 0.0f;
    float m_i = -1e30f, l_i = 0.0f;

    // staging thread mapping: rows r0 and r0+32, 16B chunk c8
    int r0 = t >> 3, c8 = t & 7;
    const u16* Kg = QKV + (long)(b * SEQ) * 3072 + 1024 + h * DK + c8 * 8;
    const u16* Vg = Vt + ((long)(b * NH + h) * DK + r0) * SEQ + c8 * 8;
    const float* Mb = Madd + b * SEQ;
    uint4 kr0 = *(const uint4*)(Kg + (long)r0 * 3072);
    uint4 kr1 = *(const uint4*)(Kg + (long)(r0 + 32) * 3072);
    uint4 vr0 = *(const uint4*)(Vg);
    uint4 vr1 = *(const uint4*)(Vg + 32 * SEQ);

    for (int kt = 0; kt < SEQ; kt += 64) {
        __syncthreads();
        *(uint4*)&Ks[r0 * 72 + c8 * 8] = kr0;
        *(uint4*)&Ks[(r0 + 32) * 72 + c8 * 8] = kr1;
        *(uint4*)&Vs[r0 * 72 + c8 * 8] = vr0;
        *(uint4*)&Vs[(r0 + 32) * 72 + c8 * 8] = vr1;
        __syncthreads();
        if (kt + 64 < SEQ) {   // prefetch next tile into regs (overlaps compute)
            kr0 = *(const uint4*)(Kg + (long)(kt + 64 + r0) * 3072);
            kr1 = *(const uint4*)(Kg + (long)(kt + 64 + r0 + 32) * 3072);
            vr0 = *(const uint4*)(Vg + kt + 64);
            vr1 = *(const uint4*)(Vg + 32 * SEQ + kt + 64);
        }

        // ---- S^T[key][q] = K Q^T ----
        floatx4 S[4];
        for (int j = 0; j < 4; j++) {
            short8 k0 = *(const short8*)&Ks[(16 * j + lm) * 72 + lq * 8];
            short8 k1 = *(const short8*)&Ks[(16 * j + lm) * 72 + 32 + lq * 8];
            floatx4 z = {0.0f, 0.0f, 0.0f, 0.0f};
            S[j] = __builtin_amdgcn_mfma_f32_16x16x32_bf16(k0, qf0, z, 0, 0, 0);
            S[j] = __builtin_amdgcn_mfma_f32_16x16x32_bf16(k1, qf1, S[j], 0, 0, 0);
        }

        // ---- additive mask + online softmax (per-lane scalar m/l) ----
        float mx = -1e30f;
        for (int j = 0; j < 4; j++) {
            floatx4 ma = *(const floatx4*)&Mb[kt + 16 * j + l4];
            for (int r = 0; r < 4; r++) {
                S[j][r] += ma[r];
                mx = fmaxf(mx, S[j][r]);
            }
        }
        mx = fmaxf(mx, __shfl_xor(mx, 16, 64));
        mx = fmaxf(mx, __shfl_xor(mx, 32, 64));
        float mn = fmaxf(m_i, mx);
        float alpha = __expf(m_i - mn);
        m_i = mn;
        float rs = 0.0f;
        for (int j = 0; j < 4; j++) {
            float p0 = __expf(S[j][0] - mn);
            float p1 = __expf(S[j][1] - mn);
            float p2 = __expf(S[j][2] - mn);
            float p3 = __expf(S[j][3] - mn);
            rs += (p0 + p1) + (p2 + p3);
            uint2 pk;
            pk.x = pack_bf16(p0, p1);
            pk.y = pack_bf16(p2, p3);
            *(uint2*)&Pw[lm * 72 + 16 * j + l4] = pk;   // P[q=lm][key]
        }
        rs += __shfl_xor(rs, 16, 64);
        rs += __shfl_xor(rs, 32, 64);
        l_i = alpha * l_i + rs;

        // redistribute alpha from col-layout (lane lm=q) to row-layout (q=lq*4+r)
        float af[4];
        for (int r = 0; r < 4; r++)
            af[r] = __shfl(alpha, (l & 48) + l4 + r, 64);
        for (int dt = 0; dt < 4; dt++)
            for (int r = 0; r < 4; r++) O[dt][r] *= af[r];

        // ---- O += P V ---- (P b128 A-frags; same-wave ds ordering via lgkmcnt)
        short8 pa0 = *(const short8*)&Pw[lm * 72 + lq * 8];
        short8 pa1 = *(const short8*)&Pw[lm * 72 + 32 + lq * 8];
        for (int dt = 0; dt < 4; dt++) {
            short8 v0 = *(const short8*)&Vs[(16 * dt + lm) * 72 + lq * 8];
            short8 v1 = *(const short8*)&Vs[(16 * dt + lm) * 72 + 32 + lq * 8];
            O[dt] = __builtin_amdgcn_mfma_f32_16x16x32_bf16(pa0, v0, O[dt], 0, 0, 0);
            O[dt] = __builtin_amdgcn_mfma_f32_16x16x32_bf16(pa1, v1, O[dt], 0, 0, 0);
        }
    }

    float inv[4];
    for (int r = 0; r < 4; r++)
        inv[r] = 1.0f / __shfl(l_i, (l & 48) + l4 + r, 64);
    for (int dt = 0; dt < 4; dt++)
        for (int r = 0; r < 4; r++) {
            long row = (long)(b * SEQ + q0 + w * 16 + l4 + r);
            ctx[row * DM + h * DK + 16 * dt + lm] = f2bf(O[dt][r] * inv[r]);
        }
}

// ---------------------------------------------------------------------------
// Launch
// ---------------------------------------------------------------------------
extern "C" void kernel_launch(void* const* d_in, const int* in_sizes, int n_in,
                              void* d_out, int out_size, void* d_ws, size_t ws_size,
                              hipStream_t stream) {
    const float* x    = (const float*)d_in[0];
    const int*   mask = (const int*)d_in[1];
    const float* Wq = (const float*)d_in[2];  const float* bq = (const float*)d_in[3];
    const float* Wk = (const float*)d_in[4];  const float* bk = (const float*)d_in[5];
    const float* Wv = (const float*)d_in[6];  const float* bv = (const float*)d_in[7];
    const float* Wo = (const float*)d_in[8];  const float* bo = (const float*)d_in[9];
    const float* W1 = (const float*)d_in[10]; const float* b1 = (const float*)d_in[11];
    const float* W2 = (const float*)d_in[12]; const float* b2 = (const float*)d_in[13];
    const float* ln1g = (const float*)d_in[14]; const float* ln1b = (const float*)d_in[15];
    const float* ln2g = (const float*)d_in[16]; const float* ln2b = (const float*)d_in[17];

    char* ws = (char*)d_ws;
    const size_t MB = 1u << 20;
    // 0-24 MB: transposed weights; peak total 136 MB
    u16* WQKVT = (u16*)(ws + 0 * MB);             // 3072x1024 bf16 (6 MB)
    u16* WoT   = (u16*)(ws + 6 * MB);             // 2 MB
    u16* W1T   = (u16*)(ws + 8 * MB);             // 8 MB
    u16* W2T   = (u16*)(ws + 16 * MB);            // 8 MB
    u16* Hbf   = (u16*)(ws + 24 * MB);            // LN out bf16 [8192][1024] (16 MB)
    u16* Vtp   = (u16*)(ws + 24 * MB);            // Vt, reuses Hbf after QKV gemm
    u16* QKVb  = (u16*)(ws + 40 * MB);            // [8192][3072] bf16 (48 MB)
    u16* CTX   = (u16*)(ws + 88 * MB);            // 16 MB
    float* X2  = (float*)(ws + 104 * MB);         // fp32 [8192][1024] (32 MB)
    float* bqkv = (float*)(ws + 104 * MB);        // 12 KB, dead before X2 written
    float* Madd = (float*)(ws + 104 * MB + 64 * 1024); // 32 KB, dead before X2
    u16* H2    = (u16*)(ws + 40 * MB);            // [8192][4096] bf16 (64 MB, 40-104)

    dim3 tb(32, 8);
    wtrans_kernel<<<dim3(DM / 32, DM / 32), tb, 0, stream>>>(Wq, WQKVT, DM, DM);
    wtrans_kernel<<<dim3(DM / 32, DM / 32), tb, 0, stream>>>(Wk, WQKVT + 1024 * 1024, DM, DM);
    wtrans_kernel<<<dim3(DM / 32, DM / 32), tb, 0, stream>>>(Wv, WQKVT + 2048 * 1024, DM, DM);
    wtrans_kernel<<<dim3(DM / 32, DM / 32), tb, 0, stream>>>(Wo, WoT, DM, DM);
    wtrans_kernel<<<dim3(DFF / 32, DM / 32), tb, 0, stream>>>(W1, W1T, DM, DFF);
    wtrans_kernel<<<dim3(DM / 32, DFF / 32), tb, 0, stream>>>(W2, W2T, DFF, DM);
    bconcat_kernel<<<12, 256, 0, stream>>>(bq, bk, bv, bqkv);
    madd_kernel<<<NTOK / 256, 256, 0, stream>>>(mask, Madd);

    // ln1
    ln_kernel<<<NTOK, 256, 0, stream>>>(x, ln1g, ln1b, Hbf);

    // fused QKV projection (bf16 out, bias, Q cols scaled by 0.125)
    gemm_kernel<<<dim3(3072 / 128, NTOK / 128), 256, 0, stream>>>(
        Hbf, WQKVT, bqkv, nullptr, QKVb, NTOK, 3072, DM, 1 | 4);

    // V -> Vt [B,H,Dk,S]  (Hbf dead after QKV gemm; region reused)
    vtrans_kernel<<<dim3(SEQ / 64, NH, BATCH), 256, 0, stream>>>(QKVb, Vtp);

    // attention
    attn_kernel<<<dim3(SEQ / 64, NH, BATCH), 256, 0, stream>>>(QKVb, Vtp, Madd, CTX);

    // x2 = x + ctx @ Wo + bo (fp32 out)
    gemm_kernel<<<dim3(DM / 128, NTOK / 128), 256, 0, stream>>>(CTX, WoT, bo, x, X2, NTOK, DM, DM, 0);

    // ln2
    ln_kernel<<<NTOK, 256, 0, stream>>>(X2, ln2g, ln2b, Hbf);

    // h2 = gelu(h @ W1 + b1) (bf16 out)
    gemm_kernel<<<dim3(DFF / 128, NTOK / 128), 256, 0, stream>>>(Hbf, W1T, b1, nullptr, H2, NTOK, DFF, DM, 3);

    // out = x2 + h2 @ W2 + b2 (fp32 out)
    gemm_kernel<<<dim3(DM / 128, NTOK / 128), 256, 0, stream>>>(H2, W2T, b2, X2, (float*)d_out, NTOK, DM, DFF, 0);
}